// Round 18
// baseline (529.009 us; speedup 1.0000x reference)
//
#include <hip/hip_runtime.h>

#define NNODES 50000
#define NEDGES 400000
#define NEA    450000
#define NG     128
#define DEGCAP 96
#define OGW    72
#define NCH    49        // ceil(NNODES/1024)
#define PREPN  1128328
#define PREPB  4408      // ceil(PREPN/256)
#define EDGEB  1563      // ceil(NEDGES/256)
#define OGB    (NG*16)   // og2 blocks: 16 chunks per graph (R6 best)
#define SEB    2000      // se4 blocks (200 edges each)

typedef unsigned short u16;
typedef unsigned int   u32;
typedef __attribute__((ext_vector_type(8))) short short8v;
typedef __attribute__((ext_vector_type(4))) float f32x4;

static inline int ceil_div(int a, int b){ return (a + b - 1)/b; }

__device__ __forceinline__ u16 f2bf(float f){
  u32 u = __builtin_bit_cast(u32, f);
  u = (u + 0x7fffu + ((u >> 16) & 1u)) >> 16;   // RNE
  return (u16)u;
}
__device__ __forceinline__ float bfLO(u32 q){ return __builtin_bit_cast(float, q << 16); }
__device__ __forceinline__ float bfHI(u32 q){ return __builtin_bit_cast(float, q & 0xffff0000u); }
__device__ __forceinline__ void gload_lds16(const u16* g, u16* l){
  __builtin_amdgcn_global_load_lds((const __attribute__((address_space(1))) void*)g,
                                   (__attribute__((address_space(3))) void*)l, 16, 0, 0);
}

// ---------------- fused: casts + ve table (blocks < PREPB) | deg+gb+gcnt ----------------
__global__ void k_prep_deg(const float* __restrict__ x, u16* __restrict__ xb,
                       const float* __restrict__ W1, u16* __restrict__ Wt1,
                       const float* __restrict__ W2, u16* __restrict__ Wt2,
                       const float* __restrict__ W3, u16* __restrict__ Wt3,
                       const float* __restrict__ We1, const float* __restrict__ ae1,
                       const float* __restrict__ We2, const float* __restrict__ ae2,
                       const float* __restrict__ We3, const float* __restrict__ ae3,
                       float* __restrict__ veall,
                       const int* __restrict__ src, const int* __restrict__ dst,
                       const int* __restrict__ batch,
                       int* __restrict__ deg, int* __restrict__ gb, int* __restrict__ gcnt){
  if (blockIdx.x >= PREPB){
    __shared__ int h[NG];
    int t = threadIdx.x;
    if (t < NG) h[t] = 0;
    __syncthreads();
    int e = (blockIdx.x - PREPB)*256 + t;
    if (e < NEDGES){
      atomicAdd(&deg[dst[e]], 1);
      int g = batch[src[e]];
      gb[e] = g;
      atomicAdd(&h[g], 1);
    }
    __syncthreads();
    if (t < NG && h[t]) atomicAdd(&gcnt[t], h[t]);
    return;
  }
  int i = blockIdx.x*blockDim.x + threadIdx.x;
  if (i < 800000){
    float4 v = ((const float4*)x)[i];
    ((ushort4*)xb)[i] = make_ushort4(f2bf(v.x), f2bf(v.y), f2bf(v.z), f2bf(v.w));
    return;
  }
  i -= 800000;
  if (i < 32768){   // Wt1 [512][64] <- W1 [64][512]
    int n = i >> 6, k = i & 63;
    Wt1[i] = f2bf(W1[(size_t)k*512 + n]);
    return;
  }
  i -= 32768;
  if (i < 262144){  // Wt2 [512][512] <- W2
    int n = i >> 9, k = i & 511;
    Wt2[i] = f2bf(W2[(size_t)k*512 + n]);
    return;
  }
  i -= 262144;
  if (i < 32768){   // Wt3 [64][512] <- W3 [512][64]
    int n = i >> 9, k = i & 511;
    Wt3[i] = f2bf(W3[(size_t)k*64 + n]);
    return;
  }
  i -= 32768;
  if (i < 648){
    const float* We; const float* ae; int H, C, basej, li;
    if (i < 288){ We = We1; ae = ae1; H = 4; C = 128; basej = 0; li = i; }
    else if (i < 576){ We = We2; ae = ae2; H = 4; C = 128; basej = 4; li = i - 288; }
    else { We = We3; ae = ae3; H = 1; C = 64; basej = 8; li = i - 576; }
    int k = li / H, h = li - k*H;
    const float* wrow = We + (size_t)k*H*C + (size_t)h*C;
    const float* arow = ae + (size_t)h*C;
    float s = 0.f;
    for (int c = 0; c < C; ++c) s += wrow[c]*arow[c];
    veall[k*9 + basej + h] = s;
  }
}

// ---------------- parallel scan ----------------
__global__ __launch_bounds__(1024) void k_chunksum(const int* __restrict__ deg, int* __restrict__ csum){
  __shared__ int s[1024];
  int t = threadIdx.x;
  int i = blockIdx.x*1024 + t;
  s[t] = (i < NNODES) ? deg[i]+1 : 0;
  __syncthreads();
  for (int o = 512; o > 0; o >>= 1){
    if (t < o) s[t] += s[t+o];
    __syncthreads();
  }
  if (t == 0) csum[blockIdx.x] = s[0];
}

__global__ __launch_bounds__(128) void k_scanmid(const int* __restrict__ csum, int* __restrict__ cbase,
                                                 const int* __restrict__ gcnt, int* __restrict__ goff,
                                                 int* __restrict__ gcur){
  __shared__ int sg[NG];
  int t = threadIdx.x;
  if (t < 64){
    int v0 = (t < NCH) ? csum[t] : 0;
    int v = v0;
    #pragma unroll
    for (int o = 1; o < 64; o <<= 1){
      int xsh = __shfl_up(v, o);
      if (t >= o) v += xsh;
    }
    if (t < NCH) cbase[t] = v - v0;
  }
  int vg = gcnt[t];
  sg[t] = vg;
  __syncthreads();
  for (int o = 1; o < NG; o <<= 1){
    int xg = (t >= o) ? sg[t-o] : 0;
    __syncthreads();
    sg[t] += xg;
    __syncthreads();
  }
  goff[t] = sg[t] - vg;
  gcur[t] = sg[t] - vg;
}

__global__ __launch_bounds__(1024) void k_scanout(const int* __restrict__ deg,
                                                  const int* __restrict__ cbase, int* __restrict__ off){
  __shared__ int s[1024];
  int t = threadIdx.x;
  int i = blockIdx.x*1024 + t;
  int v = (i < NNODES) ? deg[i]+1 : 0;
  s[t] = v;
  __syncthreads();
  for (int o = 1; o < 1024; o <<= 1){
    int xv = (t >= o) ? s[t-o] : 0;
    __syncthreads();
    s[t] += xv;
    __syncthreads();
  }
  if (i < NNODES){
    int incl = s[t] + cbase[blockIdx.x];
    off[i] = incl - v;
    if (i == NNODES-1) off[NNODES] = incl;
  }
}

// ---------------- fill + self-loop + graph-sort scatter (edgepos + sortedeid) ----------------
__global__ void k_scatter(const int* __restrict__ src, const int* __restrict__ dst,
                          const int* __restrict__ gb, const int* __restrict__ off,
                          int* __restrict__ cnt, int* __restrict__ gcur,
                          int* __restrict__ csr_src, int* __restrict__ edgepos,
                          int* __restrict__ sortedeid){
  __shared__ int lcnt[NG];
  __shared__ int lbase[NG];
  int t = threadIdx.x;
  int e = blockIdx.x*256 + t;
  if (t < NG) lcnt[t] = 0;
  __syncthreads();
  int g = -1, lr = 0;
  if (e < NEDGES){
    int d = dst[e];
    int p = off[d] + atomicAdd(&cnt[d], 1);
    csr_src[p] = src[e];
    edgepos[e] = p;
    g = gb[e];
    lr = atomicAdd(&lcnt[g], 1);
  } else {
    int n2 = e - NEDGES;
    if (n2 < NNODES){
      int q = off[n2+1] - 1;
      csr_src[q] = n2;
    }
  }
  __syncthreads();
  if (t < NG && lcnt[t]) lbase[t] = atomicAdd(&gcur[t], lcnt[t]);
  __syncthreads();
  if (g >= 0) sortedeid[lbase[g] + lr] = e;
}

// ---------------- og2: og ONLY — sorted gather, reg acc, LDS matrix reduce (R6 verified) ----------------
__global__ __launch_bounds__(256) void k_og2(const float* __restrict__ attr,
    const int* __restrict__ goff, const int* __restrict__ gcnt,
    const int* __restrict__ sortedeid, float* __restrict__ og){
  __shared__ float red[16][OGW];
  int g = blockIdx.x >> 4, chunk = blockIdx.x & 15;
  int lane = threadIdx.x & 63, w = threadIdx.x >> 6;
  int esub = lane >> 4, l16 = lane & 15;
  int slot = w*4 + esub;
  int beg = goff[g], cnt = gcnt[g];
  int cbeg = beg + ((cnt*chunk) >> 4);
  int cend = beg + ((cnt*(chunk+1)) >> 4);
  f32x4 acc  = {0.f,0.f,0.f,0.f};
  f32x4 acch = {0.f,0.f,0.f,0.f};
  for (int i0 = cbeg; i0 < cend; i0 += 32){
    int e1 = i0 + slot, e2 = i0 + 16 + slot;
    int id1 = (e1 < cend) ? sortedeid[e1] : -1;
    int id2 = (e2 < cend) ? sortedeid[e2] : -1;
    f32x4 v1 = {0.f,0.f,0.f,0.f}, v2 = {0.f,0.f,0.f,0.f};
    f32x4 h1 = {0.f,0.f,0.f,0.f}, h2 = {0.f,0.f,0.f,0.f};
    if (id1 >= 0){
      v1 = *(const f32x4*)(attr + (size_t)id1*72 + l16*4);
      if (l16 < 2) h1 = *(const f32x4*)(attr + (size_t)id1*72 + 64 + l16*4);
    }
    if (id2 >= 0){
      v2 = *(const f32x4*)(attr + (size_t)id2*72 + l16*4);
      if (l16 < 2) h2 = *(const f32x4*)(attr + (size_t)id2*72 + 64 + l16*4);
    }
    acc += v1; acc += v2;
    if (l16 < 2){ acch += h1; acch += h2; }
  }
  #pragma unroll
  for (int j = 0; j < 4; ++j) red[slot][l16*4 + j] = acc[j];
  if (l16 < 2){
    #pragma unroll
    for (int j = 0; j < 4; ++j) red[slot][64 + l16*4 + j] = acch[j];
  }
  __syncthreads();
  int t = threadIdx.x;
  if (t < 71){
    float s = 0.f;
    #pragma unroll
    for (int q = 0; q < 16; ++q) s += red[q][t];
    atomicAdd(&og[g*OGW + t], s);
  }
}

// ---------------- se4: se ONLY — natural order, fully coalesced stream, plane scatter ----------------
// 16 lanes per edge; wave covers 4 consecutive edges -> contiguous 1152B read per wave.
__global__ __launch_bounds__(256) void k_se4(const float* __restrict__ attr,
    const int* __restrict__ edgepos, const float* __restrict__ veall,
    float* __restrict__ se1, float* __restrict__ se2, float* __restrict__ se3){
  __shared__ float vel[72*9];
  int t = threadIdx.x;
  for (int i = t; i < 648; i += 256) vel[i] = veall[i];
  __syncthreads();
  int lane = t & 63, w = t >> 6;
  int esub = lane >> 4, l16 = lane & 15;
  const int EPB = (NEDGES + SEB - 1)/SEB;   // 200
  int e0 = blockIdx.x*EPB, e1 = min(e0 + EPB, NEDGES);
  for (int base = e0; base < e1; base += 16){
    int e = base + w*4 + esub;
    bool ok = (e < e1);
    f32x4 v  = {0.f,0.f,0.f,0.f};
    f32x4 vh = {0.f,0.f,0.f,0.f};
    if (ok){
      v = *(const f32x4*)(attr + (size_t)e*72 + l16*4);
      if (l16 < 2) vh = *(const f32x4*)(attr + (size_t)e*72 + 64 + l16*4);
    }
    float s[9];
    int c0 = l16*4;
    #pragma unroll
    for (int j = 0; j < 9; ++j)
      s[j] = v[0]*vel[(c0+0)*9+j] + v[1]*vel[(c0+1)*9+j]
           + v[2]*vel[(c0+2)*9+j] + v[3]*vel[(c0+3)*9+j];
    if (l16 < 2){
      int ct = 64 + l16*4;
      #pragma unroll
      for (int j = 0; j < 9; ++j)
        s[j] += vh[0]*vel[(ct+0)*9+j] + vh[1]*vel[(ct+1)*9+j]
              + vh[2]*vel[(ct+2)*9+j] + vh[3]*vel[(ct+3)*9+j];
    }
    #pragma unroll
    for (int msk = 1; msk < 16; msk <<= 1){
      #pragma unroll
      for (int j = 0; j < 9; ++j) s[j] += __shfl_xor(s[j], msk);
    }
    if (ok && l16 == 0){
      int p = edgepos[e];
      *(float4*)(se1 + (size_t)p*4) = make_float4(s[0], s[1], s[2], s[3]);
      *(float4*)(se2 + (size_t)p*4) = make_float4(s[4], s[5], s[6], s[7]);
      se3[p] = s[8];
    }
  }
}

// ---------------- gemm128: BM=BN=128, BK=64, gload_lds, fused att, LDS-staged C ----------------
__global__ __launch_bounds__(256) void k_gemm128(const u16* __restrict__ A,
    const u16* __restrict__ Bt, u16* __restrict__ C, int M, int K,
    const float* __restrict__ a_s, const float* __restrict__ a_d,
    float* __restrict__ ssrc, float* __restrict__ sdst){
  __shared__ __align__(16) u16 smem[128*128];
  u16* As = smem;
  u16* Bs = smem + 128*64;
  __shared__ float s_ps[128][2];
  __shared__ float s_pd[128][2];
  const int tid = threadIdx.x;
  const int wid = tid >> 6, lane = tid & 63;
  const int l15 = lane & 15, kslot = lane >> 4;
  const int wr = wid >> 1, wc = wid & 1;
  const int h = blockIdx.x;
  const int m0 = blockIdx.y * 128, n0 = h * 128;
  const int Nn = 512;
  f32x4 acc[4][4];
  #pragma unroll
  for (int mi = 0; mi < 4; ++mi)
    #pragma unroll
    for (int ni = 0; ni < 4; ++ni)
      acc[mi][ni] = (f32x4){0.f,0.f,0.f,0.f};

  for (int kt = 0; kt < K; kt += 64){
    #pragma unroll
    for (int r = 0; r < 4; ++r){
      int chunk = (r*4 + wid)*64 + lane;
      int row = chunk >> 3, c8 = chunk & 7;
      int srcc = c8 ^ (row & 7);
      int grow = m0 + row; if (grow > M-1) grow = M-1;
      gload_lds16(A + (size_t)grow*K + kt + srcc*8, &As[chunk*8]);
    }
    #pragma unroll
    for (int r = 0; r < 4; ++r){
      int chunk = (r*4 + wid)*64 + lane;
      int row = chunk >> 3, c8 = chunk & 7;
      int srcc = c8 ^ (row & 7);
      gload_lds16(Bt + (size_t)(n0+row)*K + kt + srcc*8, &Bs[chunk*8]);
    }
    __syncthreads();
    #pragma unroll
    for (int s = 0; s < 2; ++s){
      short8v a[4], b[4];
      #pragma unroll
      for (int mi = 0; mi < 4; ++mi){
        int row = wr*64 + mi*16 + l15;
        a[mi] = *(const short8v*)(&As[row*64 + (((s*4 + kslot) ^ (row&7))*8)]);
      }
      #pragma unroll
      for (int ni = 0; ni < 4; ++ni){
        int col = wc*64 + ni*16 + l15;
        b[ni] = *(const short8v*)(&Bs[col*64 + (((s*4 + kslot) ^ (col&7))*8)]);
      }
      #pragma unroll
      for (int mi = 0; mi < 4; ++mi)
        #pragma unroll
        for (int ni = 0; ni < 4; ++ni)
          acc[mi][ni] = __builtin_amdgcn_mfma_f32_16x16x32_bf16(a[mi], b[ni], acc[mi][ni], 0, 0, 0);
    }
    __syncthreads();
  }
  float asv[4], adv[4];
  #pragma unroll
  for (int ni = 0; ni < 4; ++ni){
    int c = wc*64 + ni*16 + l15;
    asv[ni] = a_s[h*128 + c];
    adv[ni] = a_d[h*128 + c];
  }
  #pragma unroll
  for (int mi = 0; mi < 4; ++mi){
    #pragma unroll
    for (int r = 0; r < 4; ++r){
      int row_l = wr*64 + mi*16 + kslot*4 + r;
      float ps = 0.f, pd = 0.f;
      #pragma unroll
      for (int ni = 0; ni < 4; ++ni){
        float v = acc[mi][ni][r];
        smem[row_l*128 + wc*64 + ni*16 + l15] = f2bf(v);
        ps += v*asv[ni];
        pd += v*adv[ni];
      }
      #pragma unroll
      for (int m = 8; m >= 1; m >>= 1){ ps += __shfl_xor(ps,m); pd += __shfl_xor(pd,m); }
      if (l15 == 0){ s_ps[row_l][wc] = ps; s_pd[row_l][wc] = pd; }
    }
  }
  __syncthreads();
  #pragma unroll
  for (int i = 0; i < 8; ++i){
    int c = i*256 + tid;
    int row = c >> 4, c16 = c & 15;
    int grow = m0 + row;
    if (grow < M)
      *(uint4*)(C + (size_t)grow*Nn + n0 + c16*8) = *(const uint4*)(&smem[row*128 + c16*8]);
  }
  if (tid < 128){
    int grow = m0 + tid;
    if (grow < M){
      ssrc[grow*4 + h] = s_ps[tid][0] + s_ps[tid][1];
      sdst[grow*4 + h] = s_pd[tid][0] + s_pd[tid][1];
    }
  }
}

// ---------------- gemm64 (layer 3): bf16 out, LDS-staged C, fused satt64 ----------------
__global__ __launch_bounds__(256) void k_gemm64(const u16* __restrict__ A,
    const u16* __restrict__ Bt, u16* __restrict__ C, int M,
    const float* __restrict__ a_s, const float* __restrict__ a_d,
    float* __restrict__ ssrc, float* __restrict__ sdst){
  __shared__ __align__(16) u16 As[64*64];
  __shared__ __align__(16) u16 Bs[64*64];
  const int tid = threadIdx.x;
  const int wid = tid >> 6, lane = tid & 63;
  const int l15 = lane & 15, kslot = lane >> 4;
  const int m0 = blockIdx.x * 64;
  f32x4 acc[4];
  #pragma unroll
  for (int ni = 0; ni < 4; ++ni) acc[ni] = (f32x4){0.f,0.f,0.f,0.f};
  for (int kt = 0; kt < 512; kt += 64){
    #pragma unroll
    for (int r = 0; r < 2; ++r){
      int chunk = r*256 + tid;
      int row = chunk >> 3, c8 = chunk & 7;
      int srcc = c8 ^ (row & 7);
      int grow = m0 + row; if (grow > M-1) grow = M-1;
      gload_lds16(A + (size_t)grow*512 + kt + srcc*8, &As[chunk*8]);
    }
    #pragma unroll
    for (int r = 0; r < 2; ++r){
      int chunk = r*256 + tid;
      int row = chunk >> 3, c8 = chunk & 7;
      int srcc = c8 ^ (row & 7);
      gload_lds16(Bt + (size_t)row*512 + kt + srcc*8, &Bs[chunk*8]);
    }
    __syncthreads();
    #pragma unroll
    for (int s = 0; s < 2; ++s){
      int row = wid*16 + l15;
      short8v a = *(const short8v*)(&As[row*64 + (((s*4 + kslot) ^ (row&7))*8)]);
      #pragma unroll
      for (int ni = 0; ni < 4; ++ni){
        int col = ni*16 + l15;
        short8v b = *(const short8v*)(&Bs[col*64 + (((s*4 + kslot) ^ (col&7))*8)]);
        acc[ni] = __builtin_amdgcn_mfma_f32_16x16x32_bf16(a, b, acc[ni], 0, 0, 0);
      }
    }
    __syncthreads();
  }
  #pragma unroll
  for (int r = 0; r < 4; ++r){
    int row_l = wid*16 + kslot*4 + r;
    int grow = m0 + row_l;
    float ps = 0.f, pd = 0.f;
    #pragma unroll
    for (int ni = 0; ni < 4; ++ni){
      float v = acc[ni][r];
      int c = ni*16 + l15;
      As[row_l*64 + c] = f2bf(v);
      ps += v*a_s[c];
      pd += v*a_d[c];
    }
    #pragma unroll
    for (int m = 8; m >= 1; m >>= 1){ ps += __shfl_xor(ps,m); pd += __shfl_xor(pd,m); }
    if (l15 == 0 && grow < M){ ssrc[grow] = ps; sdst[grow] = pd; }
  }
  __syncthreads();
  #pragma unroll
  for (int i = 0; i < 2; ++i){
    int c = i*256 + tid;
    int row = c >> 3, c8 = c & 7;
    int grow = m0 + row;
    if (grow < M)
      *(uint4*)(C + (size_t)grow*64 + c8*8) = *(const uint4*)(&As[row*64 + c8*8]);
  }
}

// ---------------- agg12: wave-per-node, coalesced se, unroll-4 gather ----------------
__global__ __launch_bounds__(256) void k_agg12(const u16* __restrict__ xs,
    const int* __restrict__ off, const int* __restrict__ csr_src,
    const float* __restrict__ ssrc, const float* __restrict__ sdst,
    const float* __restrict__ sep,
    const float* __restrict__ bias, u16* __restrict__ out){
  __shared__ float s_al[4][DEGCAP][4];
  __shared__ int   s_col[4][DEGCAP];
  int w = threadIdx.x >> 6, lane = threadIdx.x & 63;
  int n = blockIdx.x*4 + w;
  int beg = off[n];
  int deg = off[n+1] - beg;
  if (deg > DEGCAP) deg = DEGCAP;
  int es = lane >> 2, h = lane & 3;
  float sd = sdst[n*4+h];
  float sesum = 0.f;
  for (int e0 = 0; e0 < deg-1; e0 += 16){
    int e = e0 + es;
    if (e < deg-1){
      int col = csr_src[beg+e];
      float sr = sep[(size_t)(beg+e)*4 + h];
      sesum += sr;
      float s = ssrc[col*4+h] + sd + sr;
      s = (s > 0.f) ? s : 0.2f*s;
      s_al[w][e][h] = s;
      if (h == 0) s_col[w][e] = col;
    }
  }
  #pragma unroll
  for (int msk = 4; msk < 64; msk <<= 1) sesum += __shfl_xor(sesum, msk);
  if (es == 0){
    float slp = sesum / fmaxf((float)(deg-1), 1.0f);
    float s = ssrc[n*4+h] + sd + slp;
    s = (s > 0.f) ? s : 0.2f*s;
    s_al[w][deg-1][h] = s;
    if (h == 0) s_col[w][deg-1] = n;
  }
  float m = -1e30f;
  for (int e = es; e < deg; e += 16) m = fmaxf(m, s_al[w][e][h]);
  #pragma unroll
  for (int msk = 4; msk < 64; msk <<= 1) m = fmaxf(m, __shfl_xor(m, msk));
  float z = 0.f;
  for (int e = es; e < deg; e += 16){ float ex = __expf(s_al[w][e][h]-m); s_al[w][e][h] = ex; z += ex; }
  #pragma unroll
  for (int msk = 4; msk < 64; msk <<= 1) z += __shfl_xor(z, msk);
  float inv = 1.0f/(z + 1e-16f);
  for (int e = es; e < deg; e += 16) s_al[w][e][h] *= inv;
  int degR = (deg + 3) & ~3;
  for (int e = deg + es; e < degR; e += 16){ s_al[w][e][h] = 0.f; if (h == 0) s_col[w][e] = n; }
  __syncthreads();
  int hh = lane >> 4;
  f32x4 accA = {0.f,0.f,0.f,0.f}, accB = {0.f,0.f,0.f,0.f};
  for (int e = 0; e < degR; e += 4){
    int c0 = s_col[w][e+0], c1 = s_col[w][e+1], c2 = s_col[w][e+2], c3 = s_col[w][e+3];
    uint4 q0 = *(const uint4*)(xs + (size_t)c0*512 + lane*8);
    uint4 q1 = *(const uint4*)(xs + (size_t)c1*512 + lane*8);
    uint4 q2 = *(const uint4*)(xs + (size_t)c2*512 + lane*8);
    uint4 q3 = *(const uint4*)(xs + (size_t)c3*512 + lane*8);
    float a0 = s_al[w][e+0][hh], a1 = s_al[w][e+1][hh];
    float a2 = s_al[w][e+2][hh], a3 = s_al[w][e+3][hh];
    accA[0] += a0*bfLO(q0.x) + a1*bfLO(q1.x) + a2*bfLO(q2.x) + a3*bfLO(q3.x);
    accA[1] += a0*bfHI(q0.x) + a1*bfHI(q1.x) + a2*bfHI(q2.x) + a3*bfHI(q3.x);
    accA[2] += a0*bfLO(q0.y) + a1*bfLO(q1.y) + a2*bfLO(q2.y) + a3*bfLO(q3.y);
    accA[3] += a0*bfHI(q0.y) + a1*bfHI(q1.y) + a2*bfHI(q2.y) + a3*bfHI(q3.y);
    accB[0] += a0*bfLO(q0.z) + a1*bfLO(q1.z) + a2*bfLO(q2.z) + a3*bfLO(q3.z);
    accB[1] += a0*bfHI(q0.z) + a1*bfHI(q1.z) + a2*bfHI(q2.z) + a3*bfHI(q3.z);
    accB[2] += a0*bfLO(q0.w) + a1*bfLO(q1.w) + a2*bfLO(q2.w) + a3*bfLO(q3.w);
    accB[3] += a0*bfHI(q0.w) + a1*bfHI(q1.w) + a2*bfHI(q2.w) + a3*bfHI(q3.w);
  }
  f32x4 b0 = *(const f32x4*)(bias + lane*8);
  f32x4 b1 = *(const f32x4*)(bias + lane*8 + 4);
  short8v res;
  res[0] = (short)f2bf(fmaxf(accA[0]+b0[0], 0.f));
  res[1] = (short)f2bf(fmaxf(accA[1]+b0[1], 0.f));
  res[2] = (short)f2bf(fmaxf(accA[2]+b0[2], 0.f));
  res[3] = (short)f2bf(fmaxf(accA[3]+b0[3], 0.f));
  res[4] = (short)f2bf(fmaxf(accB[0]+b1[0], 0.f));
  res[5] = (short)f2bf(fmaxf(accB[1]+b1[1], 0.f));
  res[6] = (short)f2bf(fmaxf(accB[2]+b1[2], 0.f));
  res[7] = (short)f2bf(fmaxf(accB[3]+b1[3], 0.f));
  *(short8v*)(out + (size_t)n*512 + lane*8) = res;
}

// ---------------- agg3: wave-per-node, bf16 xs, paired-edge unroll-4 ----------------
__global__ __launch_bounds__(256) void k_agg3(const u16* __restrict__ xs,
    const int* __restrict__ off, const int* __restrict__ csr_src,
    const float* __restrict__ ssrc, const float* __restrict__ sdst,
    const float* __restrict__ se3,
    const float* __restrict__ bias, float* __restrict__ out){
  __shared__ float s_al[4][DEGCAP];
  __shared__ int   s_col[4][DEGCAP];
  int w = threadIdx.x >> 6, lane = threadIdx.x & 63;
  int n = blockIdx.x*4 + w;
  int beg = off[n];
  int deg = off[n+1] - beg;
  if (deg > DEGCAP) deg = DEGCAP;
  float sd = sdst[n];
  float sesum = 0.f;
  for (int e0 = 0; e0 < deg-1; e0 += 64){
    int e = e0 + lane;
    if (e < deg-1){
      int col = csr_src[beg+e];
      float sr = se3[beg+e];
      sesum += sr;
      float s = ssrc[col] + sd + sr;
      s = (s > 0.f) ? s : 0.2f*s;
      s_al[w][e] = s;
      s_col[w][e] = col;
    }
  }
  #pragma unroll
  for (int msk = 1; msk < 64; msk <<= 1) sesum += __shfl_xor(sesum, msk);
  if (lane == 0){
    float slp = sesum / fmaxf((float)(deg-1), 1.0f);
    float s = ssrc[n] + sd + slp;
    s = (s > 0.f) ? s : 0.2f*s;
    s_al[w][deg-1] = s;
    s_col[w][deg-1] = n;
  }
  float m = -1e30f;
  for (int e = lane; e < deg; e += 64) m = fmaxf(m, s_al[w][e]);
  #pragma unroll
  for (int msk = 1; msk < 64; msk <<= 1) m = fmaxf(m, __shfl_xor(m, msk));
  float z = 0.f;
  for (int e = lane; e < deg; e += 64){ float ex = __expf(s_al[w][e]-m); s_al[w][e] = ex; z += ex; }
  #pragma unroll
  for (int msk = 1; msk < 64; msk <<= 1) z += __shfl_xor(z, msk);
  float inv = 1.0f/(z + 1e-16f);
  for (int e = lane; e < deg; e += 64) s_al[w][e] *= inv;
  int degR = (deg + 3) & ~3;
  for (int e = deg + lane; e < degR; e += 64){ s_al[w][e] = 0.f; s_col[w][e] = n; }
  __syncthreads();
  int half = lane >> 5, cp = lane & 31;
  float a0 = 0.f, a1 = 0.f;
  for (int e = 0; e < degR; e += 4){
    int c0 = s_col[w][e + half], c1 = s_col[w][e + 2 + half];
    u32 q0 = *(const u32*)(xs + (size_t)c0*64 + cp*2);
    u32 q1 = *(const u32*)(xs + (size_t)c1*64 + cp*2);
    float al0 = s_al[w][e + half], al1 = s_al[w][e + 2 + half];
    a0 += al0*bfLO(q0) + al1*bfLO(q1);
    a1 += al0*bfHI(q0) + al1*bfHI(q1);
  }
  a0 += __shfl_xor(a0, 32);
  a1 += __shfl_xor(a1, 32);
  if (half == 0){
    float2 o;
    o.x = fmaxf(a0 + bias[cp*2+0], 0.f);
    o.y = fmaxf(a1 + bias[cp*2+1], 0.f);
    *(float2*)(out + (size_t)n*64 + cp*2) = o;
  }
}

// ---------------- pooling (batch sorted) ----------------
__global__ __launch_bounds__(64) void k_pool(const float* __restrict__ h, const int* __restrict__ batch,
                                             float* __restrict__ pooled, int* __restrict__ cntg){
  int l = threadIdx.x;
  int start = blockIdx.x * 128;
  if (start >= NNODES) return;
  int endn = min(start + 128, NNODES);
  float acc = 0.f;
  int curg = batch[start];
  int run = 0;
  for (int n = start; n < endn; ++n){
    int g = batch[n];
    if (g != curg){
      atomicAdd(&pooled[curg*64+l], acc);
      if (l == 0) atomicAdd(&cntg[curg], run);
      acc = 0.f; run = 0; curg = g;
    }
    acc += h[(size_t)n*64 + l];
    ++run;
  }
  atomicAdd(&pooled[curg*64+l], acc);
  if (l == 0) atomicAdd(&cntg[curg], run);
}

// ---------------- final FFN + softmax ----------------
__global__ void k_ffn(const float* __restrict__ pooled, const int* __restrict__ cntg,
                      const float* __restrict__ og,
                      const float* __restrict__ Wf1, const float* __restrict__ bf1,
                      const float* __restrict__ Wf2, const float* __restrict__ bf2,
                      float* __restrict__ out){
  __shared__ float z[135];
  __shared__ float z1[67];
  __shared__ float o2[2];
  int g = blockIdx.x, t = threadIdx.x;
  if (t < 64) z[t] = pooled[g*64+t] * (1.0f/fmaxf((float)cntg[g], 1.0f));
  else if (t < 135) z[t] = og[g*OGW + (t-64)];
  __syncthreads();
  if (t == 0){
    float s = 0.f;
    for (int k = 0; k < 71; ++k) s += z[64+k]*z[64+k];
    float scale = 1.0f / fmaxf(sqrtf(s), 1e-12f);
    for (int k = 0; k < 71; ++k) z[64+k] *= scale;
  }
  __syncthreads();
  if (t < 67){
    float s = bf1[t];
    for (int d = 0; d < 135; ++d) s += z[d]*Wf1[d*67+t];
    z1[t] = fmaxf(s, 0.f);
  }
  __syncthreads();
  if (t < 2){
    float s = bf2[t];
    for (int j = 0; j < 67; ++j) s += z1[j]*Wf2[j*2+t];
    o2[t] = s;
  }
  __syncthreads();
  if (t == 0){
    float m = fmaxf(o2[0], o2[1]);
    float e0 = expf(o2[0]-m), e1 = expf(o2[1]-m);
    float inv = 1.0f/(e0+e1);
    out[g*2+0] = e0*inv;
    out[g*2+1] = e1*inv;
  }
}

extern "C" void kernel_launch(void* const* d_in, const int* in_sizes, int n_in,
                              void* d_out, int out_size, void* d_ws, size_t ws_size,
                              hipStream_t stream){
  const float* x     = (const float*)d_in[0];
  const int*   ei    = (const int*)d_in[1];
  const float* eattr = (const float*)d_in[2];
  const int*   batch = (const int*)d_in[3];
  const float* W1  = (const float*)d_in[4];
  const float* We1 = (const float*)d_in[5];
  const float* as1 = (const float*)d_in[6];
  const float* ad1 = (const float*)d_in[7];
  const float* ae1 = (const float*)d_in[8];
  const float* b1  = (const float*)d_in[9];
  const float* W2  = (const float*)d_in[10];
  const float* We2 = (const float*)d_in[11];
  const float* as2 = (const float*)d_in[12];
  const float* ad2 = (const float*)d_in[13];
  const float* ae2 = (const float*)d_in[14];
  const float* b2  = (const float*)d_in[15];
  const float* W3  = (const float*)d_in[16];
  const float* We3 = (const float*)d_in[17];
  const float* as3 = (const float*)d_in[18];
  const float* ad3 = (const float*)d_in[19];
  const float* ae3 = (const float*)d_in[20];
  const float* b3  = (const float*)d_in[21];
  const float* Wf1 = (const float*)d_in[22];
  const float* bf1 = (const float*)d_in[23];
  const float* Wf2 = (const float*)d_in[24];
  const float* bf2 = (const float*)d_in[25];
  (void)in_sizes; (void)n_in; (void)out_size; (void)ws_size;
  const int* src = ei;
  const int* dst = ei + NEDGES;
  float* out = (float*)d_out;

  char* base = (char*)d_ws;
  size_t woff = 0;
  auto alloc = [&](size_t bytes)->char*{
    char* p = base + woff;
    woff += (bytes + 255) & ~(size_t)255;
    return p;
  };
  u16*   xsb    = (u16*)  alloc((size_t)NNODES*512*2);
  u16*   hb     = (u16*)  alloc((size_t)NNODES*512*2);
  u16*   xs3b   = (u16*)  alloc((size_t)NNODES*64*2);
  float* h3     = (float*)alloc((size_t)NNODES*64*4);
  u16*   xb     = (u16*)  alloc((size_t)NNODES*64*2);
  u16*   Wt1    = (u16*)  alloc((size_t)512*64*2);
  u16*   Wt2    = (u16*)  alloc((size_t)512*512*2);
  u16*   Wt3    = (u16*)  alloc((size_t)64*512*2);
  float* se1    = (float*)alloc((size_t)NEA*4*4);
  float* se2    = (float*)alloc((size_t)NEA*4*4);
  float* se3    = (float*)alloc((size_t)NEA*4);
  float* ssrc   = (float*)alloc((size_t)NNODES*4*4);
  float* sdst   = (float*)alloc((size_t)NNODES*4*4);
  float* veall  = (float*)alloc(72*9*4);
  int*   gb     = (int*)alloc((size_t)NEDGES*4);
  int*   csroff = (int*)alloc((size_t)(NNODES+1)*4);
  int*   csrsrc = (int*)alloc((size_t)NEA*4);
  int*   edgepos= (int*)alloc((size_t)NEDGES*4);
  int*   sortedeid = (int*)alloc((size_t)NEDGES*4);
  int*   goff   = (int*)alloc(NG*4);
  int*   gcur   = (int*)alloc(NG*4);
  int*   csum   = (int*)alloc(NCH*4);
  int*   cbase  = (int*)alloc(NCH*4);
  // ---- zero-initialized region (single memset) ----
  size_t z0 = woff;
  int*   deg    = (int*)alloc((size_t)NNODES*4);
  int*   cnt    = (int*)alloc((size_t)NNODES*4);
  int*   gcnt   = (int*)alloc(NG*4);
  float* og     = (float*)alloc((size_t)NG*OGW*4);
  float* pooled = (float*)alloc((size_t)NG*64*4);
  int*   cntg   = (int*)alloc((size_t)NG*4);
  size_t zlen = woff - z0;

  hipMemsetAsync(base + z0, 0, zlen, stream);

  // prep (casts + ve) fused with deg/gb/gcnt
  k_prep_deg<<<PREPB + EDGEB,256,0,stream>>>(
      x, xb, W1, Wt1, W2, Wt2, W3, Wt3, We1, ae1, We2, ae2, We3, ae3, veall,
      src, dst, batch, deg, gb, gcnt);

  // parallel scans
  k_chunksum<<<NCH,1024,0,stream>>>(deg, csum);
  k_scanmid <<<1,128,0,stream>>>(csum, cbase, gcnt, goff, gcur);
  k_scanout <<<NCH,1024,0,stream>>>(deg, cbase, csroff);

  k_scatter<<<ceil_div(NEDGES+NNODES,256),256,0,stream>>>(src, dst, gb, csroff, cnt, gcur,
                                                          csrsrc, edgepos, sortedeid);

  // og: sorted gather (og only); se: natural-order coalesced stream
  k_og2<<<OGB,256,0,stream>>>(eattr, goff, gcnt, sortedeid, og);
  k_se4<<<SEB,256,0,stream>>>(eattr, edgepos, veall, se1, se2, se3);

  dim3 g128(4, ceil_div(NNODES,128));

  // ---- layer 1 ----
  k_gemm128<<<g128,256,0,stream>>>(xb, Wt1, xsb, NNODES, 64, as1, ad1, ssrc, sdst);
  k_agg12<<<NNODES/4,256,0,stream>>>(xsb, csroff, csrsrc, ssrc, sdst, se1, b1, hb);

  // ---- layer 2 ----
  k_gemm128<<<g128,256,0,stream>>>(hb, Wt2, xsb, NNODES, 512, as2, ad2, ssrc, sdst);
  k_agg12<<<NNODES/4,256,0,stream>>>(xsb, csroff, csrsrc, ssrc, sdst, se2, b2, hb);

  // ---- layer 3 ----
  k_gemm64<<<ceil_div(NNODES,64),256,0,stream>>>(hb, Wt3, xs3b, NNODES, as3, ad3, ssrc, sdst);
  k_agg3<<<NNODES/4,256,0,stream>>>(xs3b, csroff, csrsrc, ssrc, sdst, se3, b3, h3);

  // ---- pool + FFN ----
  k_pool<<<ceil_div(NNODES,128),64,0,stream>>>(h3, batch, pooled, cntg);
  k_ffn <<<NG,192,0,stream>>>(pooled, cntg, og, Wf1, bf1, Wf2, bf2, out);
}

// Round 19
// 508.679 us; speedup vs baseline: 1.0400x; 1.0400x over previous
//
#include <hip/hip_runtime.h>

#define NNODES 50000
#define NEDGES 400000
#define NEA    450000
#define NG     128
#define DEGCAP 96
#define OGW    72
#define NCH    49        // ceil(NNODES/1024)
#define PREPN  1128328
#define PREPB  4408      // ceil(PREPN/256)
#define EDGEB  1563      // ceil(NEDGES/256)
#define OGB    (NG*16)   // edge3 blocks: 16 chunks per graph (best known)

typedef unsigned short u16;
typedef unsigned int   u32;
typedef __attribute__((ext_vector_type(8))) short short8v;
typedef __attribute__((ext_vector_type(4))) float f32x4;

static inline int ceil_div(int a, int b){ return (a + b - 1)/b; }

__device__ __forceinline__ u16 f2bf(float f){
  u32 u = __builtin_bit_cast(u32, f);
  u = (u + 0x7fffu + ((u >> 16) & 1u)) >> 16;   // RNE
  return (u16)u;
}
__device__ __forceinline__ float bfLO(u32 q){ return __builtin_bit_cast(float, q << 16); }
__device__ __forceinline__ float bfHI(u32 q){ return __builtin_bit_cast(float, q & 0xffff0000u); }
__device__ __forceinline__ void gload_lds16(const u16* g, u16* l){
  __builtin_amdgcn_global_load_lds((const __attribute__((address_space(1))) void*)g,
                                   (__attribute__((address_space(3))) void*)l, 16, 0, 0);
}

// ---------------- fused: casts + ve table (blocks < PREPB) | deg+gb+gcnt ----------------
__global__ void k_prep_deg(const float* __restrict__ x, u16* __restrict__ xb,
                       const float* __restrict__ W1, u16* __restrict__ Wt1,
                       const float* __restrict__ W2, u16* __restrict__ Wt2,
                       const float* __restrict__ W3, u16* __restrict__ Wt3,
                       const float* __restrict__ We1, const float* __restrict__ ae1,
                       const float* __restrict__ We2, const float* __restrict__ ae2,
                       const float* __restrict__ We3, const float* __restrict__ ae3,
                       float* __restrict__ veall,
                       const int* __restrict__ src, const int* __restrict__ dst,
                       const int* __restrict__ batch,
                       int* __restrict__ deg, int* __restrict__ gb, int* __restrict__ gcnt){
  if (blockIdx.x >= PREPB){
    __shared__ int h[NG];
    int t = threadIdx.x;
    if (t < NG) h[t] = 0;
    __syncthreads();
    int e = (blockIdx.x - PREPB)*256 + t;
    if (e < NEDGES){
      atomicAdd(&deg[dst[e]], 1);
      int g = batch[src[e]];
      gb[e] = g;
      atomicAdd(&h[g], 1);
    }
    __syncthreads();
    if (t < NG && h[t]) atomicAdd(&gcnt[t], h[t]);
    return;
  }
  int i = blockIdx.x*blockDim.x + threadIdx.x;
  if (i < 800000){
    float4 v = ((const float4*)x)[i];
    ((ushort4*)xb)[i] = make_ushort4(f2bf(v.x), f2bf(v.y), f2bf(v.z), f2bf(v.w));
    return;
  }
  i -= 800000;
  if (i < 32768){   // Wt1 [512][64] <- W1 [64][512]
    int n = i >> 6, k = i & 63;
    Wt1[i] = f2bf(W1[(size_t)k*512 + n]);
    return;
  }
  i -= 32768;
  if (i < 262144){  // Wt2 [512][512] <- W2
    int n = i >> 9, k = i & 511;
    Wt2[i] = f2bf(W2[(size_t)k*512 + n]);
    return;
  }
  i -= 262144;
  if (i < 32768){   // Wt3 [64][512] <- W3 [512][64]
    int n = i >> 9, k = i & 511;
    Wt3[i] = f2bf(W3[(size_t)k*64 + n]);
    return;
  }
  i -= 32768;
  if (i < 648){
    const float* We; const float* ae; int H, C, basej, li;
    if (i < 288){ We = We1; ae = ae1; H = 4; C = 128; basej = 0; li = i; }
    else if (i < 576){ We = We2; ae = ae2; H = 4; C = 128; basej = 4; li = i - 288; }
    else { We = We3; ae = ae3; H = 1; C = 64; basej = 8; li = i - 576; }
    int k = li / H, h = li - k*H;
    const float* wrow = We + (size_t)k*H*C + (size_t)h*C;
    const float* arow = ae + (size_t)h*C;
    float s = 0.f;
    for (int c = 0; c < C; ++c) s += wrow[c]*arow[c];
    veall[k*9 + basej + h] = s;
  }
}

// ---------------- parallel scan ----------------
__global__ __launch_bounds__(1024) void k_chunksum(const int* __restrict__ deg, int* __restrict__ csum){
  __shared__ int s[1024];
  int t = threadIdx.x;
  int i = blockIdx.x*1024 + t;
  s[t] = (i < NNODES) ? deg[i]+1 : 0;
  __syncthreads();
  for (int o = 512; o > 0; o >>= 1){
    if (t < o) s[t] += s[t+o];
    __syncthreads();
  }
  if (t == 0) csum[blockIdx.x] = s[0];
}

__global__ __launch_bounds__(128) void k_scanmid(const int* __restrict__ csum, int* __restrict__ cbase,
                                                 const int* __restrict__ gcnt, int* __restrict__ goff,
                                                 int* __restrict__ gcur){
  __shared__ int sg[NG];
  int t = threadIdx.x;
  if (t < 64){
    int v0 = (t < NCH) ? csum[t] : 0;
    int v = v0;
    #pragma unroll
    for (int o = 1; o < 64; o <<= 1){
      int xsh = __shfl_up(v, o);
      if (t >= o) v += xsh;
    }
    if (t < NCH) cbase[t] = v - v0;
  }
  int vg = gcnt[t];
  sg[t] = vg;
  __syncthreads();
  for (int o = 1; o < NG; o <<= 1){
    int xg = (t >= o) ? sg[t-o] : 0;
    __syncthreads();
    sg[t] += xg;
    __syncthreads();
  }
  goff[t] = sg[t] - vg;
  gcur[t] = sg[t] - vg;
}

__global__ __launch_bounds__(1024) void k_scanout(const int* __restrict__ deg,
                                                  const int* __restrict__ cbase, int* __restrict__ off){
  __shared__ int s[1024];
  int t = threadIdx.x;
  int i = blockIdx.x*1024 + t;
  int v = (i < NNODES) ? deg[i]+1 : 0;
  s[t] = v;
  __syncthreads();
  for (int o = 1; o < 1024; o <<= 1){
    int xv = (t >= o) ? s[t-o] : 0;
    __syncthreads();
    s[t] += xv;
    __syncthreads();
  }
  if (i < NNODES){
    int incl = s[t] + cbase[blockIdx.x];
    off[i] = incl - v;
    if (i == NNODES-1) off[NNODES] = incl;
  }
}

// ---------------- fill + self-loop + graph-sort scatter (pair = {eid, csrpos}) ----------------
__global__ void k_scatter(const int* __restrict__ src, const int* __restrict__ dst,
                          const int* __restrict__ gb, const int* __restrict__ off,
                          int* __restrict__ cnt, int* __restrict__ gcur,
                          int* __restrict__ csr_src, int2* __restrict__ sortedpair){
  __shared__ int lcnt[NG];
  __shared__ int lbase[NG];
  int t = threadIdx.x;
  int e = blockIdx.x*256 + t;
  if (t < NG) lcnt[t] = 0;
  __syncthreads();
  int g = -1, lr = 0, p = 0;
  if (e < NEDGES){
    int d = dst[e];
    p = off[d] + atomicAdd(&cnt[d], 1);
    csr_src[p] = src[e];
    g = gb[e];
    lr = atomicAdd(&lcnt[g], 1);
  } else {
    int n2 = e - NEDGES;
    if (n2 < NNODES){
      int q = off[n2+1] - 1;
      csr_src[q] = n2;
    }
  }
  __syncthreads();
  if (t < NG && lcnt[t]) lbase[t] = atomicAdd(&gcur[t], lcnt[t]);
  __syncthreads();
  if (g >= 0) sortedpair[lbase[g] + lr] = make_int2(e, p);
}

// ---------------- edge3: ONE sorted-gather eattr pass -> og (reg acc) + se (shfl) ----------------
// grid NG*16; block = one graph-chunk. 16 lanes/edge, ILP-2, int2 pair loads.
__global__ __launch_bounds__(256) void k_edge3(const float* __restrict__ attr,
    const int* __restrict__ goff, const int* __restrict__ gcnt,
    const int2* __restrict__ sortedpair, const float* __restrict__ veall,
    float* __restrict__ se1, float* __restrict__ se2, float* __restrict__ se3,
    float* __restrict__ og){
  __shared__ float red[16][OGW];
  __shared__ float vel[72*9];
  int t = threadIdx.x;
  for (int i = t; i < 648; i += 256) vel[i] = veall[i];
  int g = blockIdx.x >> 4, chunk = blockIdx.x & 15;
  int lane = t & 63, w = t >> 6;
  int esub = lane >> 4, l16 = lane & 15;
  int slot = w*4 + esub;
  int beg = goff[g], cnt = gcnt[g];
  int cbeg = beg + ((cnt*chunk) >> 4);
  int cend = beg + ((cnt*(chunk+1)) >> 4);
  f32x4 acc  = {0.f,0.f,0.f,0.f};
  f32x4 acch = {0.f,0.f,0.f,0.f};
  __syncthreads();
  for (int i0 = cbeg; i0 < cend; i0 += 32){
    int p1 = i0 + slot, p2 = i0 + 16 + slot;
    int2 pe1 = (p1 < cend) ? sortedpair[p1] : make_int2(-1, 0);
    int2 pe2 = (p2 < cend) ? sortedpair[p2] : make_int2(-1, 0);
    f32x4 v1 = {0.f,0.f,0.f,0.f}, v2 = {0.f,0.f,0.f,0.f};
    f32x4 h1 = {0.f,0.f,0.f,0.f}, h2 = {0.f,0.f,0.f,0.f};
    if (pe1.x >= 0){
      v1 = *(const f32x4*)(attr + (size_t)pe1.x*72 + l16*4);
      if (l16 < 2) h1 = *(const f32x4*)(attr + (size_t)pe1.x*72 + 64 + l16*4);
    }
    if (pe2.x >= 0){
      v2 = *(const f32x4*)(attr + (size_t)pe2.x*72 + l16*4);
      if (l16 < 2) h2 = *(const f32x4*)(attr + (size_t)pe2.x*72 + 64 + l16*4);
    }
    acc += v1; acc += v2;
    if (l16 < 2){ acch += h1; acch += h2; }
    // se partial dots for both edges
    float s1[9], s2[9];
    int c0 = l16*4;
    #pragma unroll
    for (int j = 0; j < 9; ++j){
      s1[j] = v1[0]*vel[(c0+0)*9+j] + v1[1]*vel[(c0+1)*9+j]
            + v1[2]*vel[(c0+2)*9+j] + v1[3]*vel[(c0+3)*9+j];
      s2[j] = v2[0]*vel[(c0+0)*9+j] + v2[1]*vel[(c0+1)*9+j]
            + v2[2]*vel[(c0+2)*9+j] + v2[3]*vel[(c0+3)*9+j];
    }
    if (l16 < 2){
      int ct = 64 + l16*4;
      #pragma unroll
      for (int j = 0; j < 9; ++j){
        s1[j] += h1[0]*vel[(ct+0)*9+j] + h1[1]*vel[(ct+1)*9+j]
               + h1[2]*vel[(ct+2)*9+j] + h1[3]*vel[(ct+3)*9+j];
        s2[j] += h2[0]*vel[(ct+0)*9+j] + h2[1]*vel[(ct+1)*9+j]
               + h2[2]*vel[(ct+2)*9+j] + h2[3]*vel[(ct+3)*9+j];
      }
    }
    #pragma unroll
    for (int msk = 1; msk < 16; msk <<= 1){
      #pragma unroll
      for (int j = 0; j < 9; ++j){ s1[j] += __shfl_xor(s1[j], msk); s2[j] += __shfl_xor(s2[j], msk); }
    }
    if (l16 == 0 && pe1.x >= 0){
      int p = pe1.y;
      *(float4*)(se1 + (size_t)p*4) = make_float4(s1[0], s1[1], s1[2], s1[3]);
      *(float4*)(se2 + (size_t)p*4) = make_float4(s1[4], s1[5], s1[6], s1[7]);
      se3[p] = s1[8];
    }
    if (l16 == 1 && pe2.x >= 0){
      int p = pe2.y;
      *(float4*)(se1 + (size_t)p*4) = make_float4(s2[0], s2[1], s2[2], s2[3]);
      *(float4*)(se2 + (size_t)p*4) = make_float4(s2[4], s2[5], s2[6], s2[7]);
      se3[p] = s2[8];
    }
  }
  #pragma unroll
  for (int j = 0; j < 4; ++j) red[slot][l16*4 + j] = acc[j];
  if (l16 < 2){
    #pragma unroll
    for (int j = 0; j < 4; ++j) red[slot][64 + l16*4 + j] = acch[j];
  }
  __syncthreads();
  if (t < 71){
    float s = 0.f;
    #pragma unroll
    for (int q = 0; q < 16; ++q) s += red[q][t];
    atomicAdd(&og[g*OGW + t], s);
  }
}

// ---------------- gemm128: BM=BN=128, BK=64, gload_lds, fused att, LDS-staged C ----------------
__global__ __launch_bounds__(256) void k_gemm128(const u16* __restrict__ A,
    const u16* __restrict__ Bt, u16* __restrict__ C, int M, int K,
    const float* __restrict__ a_s, const float* __restrict__ a_d,
    float* __restrict__ ssrc, float* __restrict__ sdst){
  __shared__ __align__(16) u16 smem[128*128];
  u16* As = smem;
  u16* Bs = smem + 128*64;
  __shared__ float s_ps[128][2];
  __shared__ float s_pd[128][2];
  const int tid = threadIdx.x;
  const int wid = tid >> 6, lane = tid & 63;
  const int l15 = lane & 15, kslot = lane >> 4;
  const int wr = wid >> 1, wc = wid & 1;
  const int h = blockIdx.x;
  const int m0 = blockIdx.y * 128, n0 = h * 128;
  const int Nn = 512;
  f32x4 acc[4][4];
  #pragma unroll
  for (int mi = 0; mi < 4; ++mi)
    #pragma unroll
    for (int ni = 0; ni < 4; ++ni)
      acc[mi][ni] = (f32x4){0.f,0.f,0.f,0.f};

  for (int kt = 0; kt < K; kt += 64){
    #pragma unroll
    for (int r = 0; r < 4; ++r){
      int chunk = (r*4 + wid)*64 + lane;
      int row = chunk >> 3, c8 = chunk & 7;
      int srcc = c8 ^ (row & 7);
      int grow = m0 + row; if (grow > M-1) grow = M-1;
      gload_lds16(A + (size_t)grow*K + kt + srcc*8, &As[chunk*8]);
    }
    #pragma unroll
    for (int r = 0; r < 4; ++r){
      int chunk = (r*4 + wid)*64 + lane;
      int row = chunk >> 3, c8 = chunk & 7;
      int srcc = c8 ^ (row & 7);
      gload_lds16(Bt + (size_t)(n0+row)*K + kt + srcc*8, &Bs[chunk*8]);
    }
    __syncthreads();
    #pragma unroll
    for (int s = 0; s < 2; ++s){
      short8v a[4], b[4];
      #pragma unroll
      for (int mi = 0; mi < 4; ++mi){
        int row = wr*64 + mi*16 + l15;
        a[mi] = *(const short8v*)(&As[row*64 + (((s*4 + kslot) ^ (row&7))*8)]);
      }
      #pragma unroll
      for (int ni = 0; ni < 4; ++ni){
        int col = wc*64 + ni*16 + l15;
        b[ni] = *(const short8v*)(&Bs[col*64 + (((s*4 + kslot) ^ (col&7))*8)]);
      }
      #pragma unroll
      for (int mi = 0; mi < 4; ++mi)
        #pragma unroll
        for (int ni = 0; ni < 4; ++ni)
          acc[mi][ni] = __builtin_amdgcn_mfma_f32_16x16x32_bf16(a[mi], b[ni], acc[mi][ni], 0, 0, 0);
    }
    __syncthreads();
  }
  float asv[4], adv[4];
  #pragma unroll
  for (int ni = 0; ni < 4; ++ni){
    int c = wc*64 + ni*16 + l15;
    asv[ni] = a_s[h*128 + c];
    adv[ni] = a_d[h*128 + c];
  }
  #pragma unroll
  for (int mi = 0; mi < 4; ++mi){
    #pragma unroll
    for (int r = 0; r < 4; ++r){
      int row_l = wr*64 + mi*16 + kslot*4 + r;
      float ps = 0.f, pd = 0.f;
      #pragma unroll
      for (int ni = 0; ni < 4; ++ni){
        float v = acc[mi][ni][r];
        smem[row_l*128 + wc*64 + ni*16 + l15] = f2bf(v);
        ps += v*asv[ni];
        pd += v*adv[ni];
      }
      #pragma unroll
      for (int m = 8; m >= 1; m >>= 1){ ps += __shfl_xor(ps,m); pd += __shfl_xor(pd,m); }
      if (l15 == 0){ s_ps[row_l][wc] = ps; s_pd[row_l][wc] = pd; }
    }
  }
  __syncthreads();
  #pragma unroll
  for (int i = 0; i < 8; ++i){
    int c = i*256 + tid;
    int row = c >> 4, c16 = c & 15;
    int grow = m0 + row;
    if (grow < M)
      *(uint4*)(C + (size_t)grow*Nn + n0 + c16*8) = *(const uint4*)(&smem[row*128 + c16*8]);
  }
  if (tid < 128){
    int grow = m0 + tid;
    if (grow < M){
      ssrc[grow*4 + h] = s_ps[tid][0] + s_ps[tid][1];
      sdst[grow*4 + h] = s_pd[tid][0] + s_pd[tid][1];
    }
  }
}

// ---------------- gemm64 (layer 3): bf16 out, LDS-staged C, fused satt64 ----------------
__global__ __launch_bounds__(256) void k_gemm64(const u16* __restrict__ A,
    const u16* __restrict__ Bt, u16* __restrict__ C, int M,
    const float* __restrict__ a_s, const float* __restrict__ a_d,
    float* __restrict__ ssrc, float* __restrict__ sdst){
  __shared__ __align__(16) u16 As[64*64];
  __shared__ __align__(16) u16 Bs[64*64];
  const int tid = threadIdx.x;
  const int wid = tid >> 6, lane = tid & 63;
  const int l15 = lane & 15, kslot = lane >> 4;
  const int m0 = blockIdx.x * 64;
  f32x4 acc[4];
  #pragma unroll
  for (int ni = 0; ni < 4; ++ni) acc[ni] = (f32x4){0.f,0.f,0.f,0.f};
  for (int kt = 0; kt < 512; kt += 64){
    #pragma unroll
    for (int r = 0; r < 2; ++r){
      int chunk = r*256 + tid;
      int row = chunk >> 3, c8 = chunk & 7;
      int srcc = c8 ^ (row & 7);
      int grow = m0 + row; if (grow > M-1) grow = M-1;
      gload_lds16(A + (size_t)grow*512 + kt + srcc*8, &As[chunk*8]);
    }
    #pragma unroll
    for (int r = 0; r < 2; ++r){
      int chunk = r*256 + tid;
      int row = chunk >> 3, c8 = chunk & 7;
      int srcc = c8 ^ (row & 7);
      gload_lds16(Bt + (size_t)row*512 + kt + srcc*8, &Bs[chunk*8]);
    }
    __syncthreads();
    #pragma unroll
    for (int s = 0; s < 2; ++s){
      int row = wid*16 + l15;
      short8v a = *(const short8v*)(&As[row*64 + (((s*4 + kslot) ^ (row&7))*8)]);
      #pragma unroll
      for (int ni = 0; ni < 4; ++ni){
        int col = ni*16 + l15;
        short8v b = *(const short8v*)(&Bs[col*64 + (((s*4 + kslot) ^ (col&7))*8)]);
        acc[ni] = __builtin_amdgcn_mfma_f32_16x16x32_bf16(a, b, acc[ni], 0, 0, 0);
      }
    }
    __syncthreads();
  }
  #pragma unroll
  for (int r = 0; r < 4; ++r){
    int row_l = wid*16 + kslot*4 + r;
    int grow = m0 + row_l;
    float ps = 0.f, pd = 0.f;
    #pragma unroll
    for (int ni = 0; ni < 4; ++ni){
      float v = acc[ni][r];
      int c = ni*16 + l15;
      As[row_l*64 + c] = f2bf(v);
      ps += v*a_s[c];
      pd += v*a_d[c];
    }
    #pragma unroll
    for (int m = 8; m >= 1; m >>= 1){ ps += __shfl_xor(ps,m); pd += __shfl_xor(pd,m); }
    if (l15 == 0 && grow < M){ ssrc[grow] = ps; sdst[grow] = pd; }
  }
  __syncthreads();
  #pragma unroll
  for (int i = 0; i < 2; ++i){
    int c = i*256 + tid;
    int row = c >> 3, c8 = c & 7;
    int grow = m0 + row;
    if (grow < M)
      *(uint4*)(C + (size_t)grow*64 + c8*8) = *(const uint4*)(&As[row*64 + c8*8]);
  }
}

// ---------------- agg12: wave-per-node, coalesced se, unroll-4 gather ----------------
__global__ __launch_bounds__(256) void k_agg12(const u16* __restrict__ xs,
    const int* __restrict__ off, const int* __restrict__ csr_src,
    const float* __restrict__ ssrc, const float* __restrict__ sdst,
    const float* __restrict__ sep,
    const float* __restrict__ bias, u16* __restrict__ out){
  __shared__ float s_al[4][DEGCAP][4];
  __shared__ int   s_col[4][DEGCAP];
  int w = threadIdx.x >> 6, lane = threadIdx.x & 63;
  int n = blockIdx.x*4 + w;
  int beg = off[n];
  int deg = off[n+1] - beg;
  if (deg > DEGCAP) deg = DEGCAP;
  int es = lane >> 2, h = lane & 3;
  float sd = sdst[n*4+h];
  float sesum = 0.f;
  for (int e0 = 0; e0 < deg-1; e0 += 16){
    int e = e0 + es;
    if (e < deg-1){
      int col = csr_src[beg+e];
      float sr = sep[(size_t)(beg+e)*4 + h];
      sesum += sr;
      float s = ssrc[col*4+h] + sd + sr;
      s = (s > 0.f) ? s : 0.2f*s;
      s_al[w][e][h] = s;
      if (h == 0) s_col[w][e] = col;
    }
  }
  #pragma unroll
  for (int msk = 4; msk < 64; msk <<= 1) sesum += __shfl_xor(sesum, msk);
  if (es == 0){
    float slp = sesum / fmaxf((float)(deg-1), 1.0f);
    float s = ssrc[n*4+h] + sd + slp;
    s = (s > 0.f) ? s : 0.2f*s;
    s_al[w][deg-1][h] = s;
    if (h == 0) s_col[w][deg-1] = n;
  }
  float m = -1e30f;
  for (int e = es; e < deg; e += 16) m = fmaxf(m, s_al[w][e][h]);
  #pragma unroll
  for (int msk = 4; msk < 64; msk <<= 1) m = fmaxf(m, __shfl_xor(m, msk));
  float z = 0.f;
  for (int e = es; e < deg; e += 16){ float ex = __expf(s_al[w][e][h]-m); s_al[w][e][h] = ex; z += ex; }
  #pragma unroll
  for (int msk = 4; msk < 64; msk <<= 1) z += __shfl_xor(z, msk);
  float inv = 1.0f/(z + 1e-16f);
  for (int e = es; e < deg; e += 16) s_al[w][e][h] *= inv;
  int degR = (deg + 3) & ~3;
  for (int e = deg + es; e < degR; e += 16){ s_al[w][e][h] = 0.f; if (h == 0) s_col[w][e] = n; }
  __syncthreads();
  int hh = lane >> 4;
  f32x4 accA = {0.f,0.f,0.f,0.f}, accB = {0.f,0.f,0.f,0.f};
  for (int e = 0; e < degR; e += 4){
    int c0 = s_col[w][e+0], c1 = s_col[w][e+1], c2 = s_col[w][e+2], c3 = s_col[w][e+3];
    uint4 q0 = *(const uint4*)(xs + (size_t)c0*512 + lane*8);
    uint4 q1 = *(const uint4*)(xs + (size_t)c1*512 + lane*8);
    uint4 q2 = *(const uint4*)(xs + (size_t)c2*512 + lane*8);
    uint4 q3 = *(const uint4*)(xs + (size_t)c3*512 + lane*8);
    float a0 = s_al[w][e+0][hh], a1 = s_al[w][e+1][hh];
    float a2 = s_al[w][e+2][hh], a3 = s_al[w][e+3][hh];
    accA[0] += a0*bfLO(q0.x) + a1*bfLO(q1.x) + a2*bfLO(q2.x) + a3*bfLO(q3.x);
    accA[1] += a0*bfHI(q0.x) + a1*bfHI(q1.x) + a2*bfHI(q2.x) + a3*bfHI(q3.x);
    accA[2] += a0*bfLO(q0.y) + a1*bfLO(q1.y) + a2*bfLO(q2.y) + a3*bfLO(q3.y);
    accA[3] += a0*bfHI(q0.y) + a1*bfHI(q1.y) + a2*bfHI(q2.y) + a3*bfHI(q3.y);
    accB[0] += a0*bfLO(q0.z) + a1*bfLO(q1.z) + a2*bfLO(q2.z) + a3*bfLO(q3.z);
    accB[1] += a0*bfHI(q0.z) + a1*bfHI(q1.z) + a2*bfHI(q2.z) + a3*bfHI(q3.z);
    accB[2] += a0*bfLO(q0.w) + a1*bfLO(q1.w) + a2*bfLO(q2.w) + a3*bfLO(q3.w);
    accB[3] += a0*bfHI(q0.w) + a1*bfHI(q1.w) + a2*bfHI(q2.w) + a3*bfHI(q3.w);
  }
  f32x4 b0 = *(const f32x4*)(bias + lane*8);
  f32x4 b1 = *(const f32x4*)(bias + lane*8 + 4);
  short8v res;
  res[0] = (short)f2bf(fmaxf(accA[0]+b0[0], 0.f));
  res[1] = (short)f2bf(fmaxf(accA[1]+b0[1], 0.f));
  res[2] = (short)f2bf(fmaxf(accA[2]+b0[2], 0.f));
  res[3] = (short)f2bf(fmaxf(accA[3]+b0[3], 0.f));
  res[4] = (short)f2bf(fmaxf(accB[0]+b1[0], 0.f));
  res[5] = (short)f2bf(fmaxf(accB[1]+b1[1], 0.f));
  res[6] = (short)f2bf(fmaxf(accB[2]+b1[2], 0.f));
  res[7] = (short)f2bf(fmaxf(accB[3]+b1[3], 0.f));
  *(short8v*)(out + (size_t)n*512 + lane*8) = res;
}

// ---------------- agg3: wave-per-node, bf16 xs, paired-edge unroll-4 ----------------
__global__ __launch_bounds__(256) void k_agg3(const u16* __restrict__ xs,
    const int* __restrict__ off, const int* __restrict__ csr_src,
    const float* __restrict__ ssrc, const float* __restrict__ sdst,
    const float* __restrict__ se3,
    const float* __restrict__ bias, float* __restrict__ out){
  __shared__ float s_al[4][DEGCAP];
  __shared__ int   s_col[4][DEGCAP];
  int w = threadIdx.x >> 6, lane = threadIdx.x & 63;
  int n = blockIdx.x*4 + w;
  int beg = off[n];
  int deg = off[n+1] - beg;
  if (deg > DEGCAP) deg = DEGCAP;
  float sd = sdst[n];
  float sesum = 0.f;
  for (int e0 = 0; e0 < deg-1; e0 += 64){
    int e = e0 + lane;
    if (e < deg-1){
      int col = csr_src[beg+e];
      float sr = se3[beg+e];
      sesum += sr;
      float s = ssrc[col] + sd + sr;
      s = (s > 0.f) ? s : 0.2f*s;
      s_al[w][e] = s;
      s_col[w][e] = col;
    }
  }
  #pragma unroll
  for (int msk = 1; msk < 64; msk <<= 1) sesum += __shfl_xor(sesum, msk);
  if (lane == 0){
    float slp = sesum / fmaxf((float)(deg-1), 1.0f);
    float s = ssrc[n] + sd + slp;
    s = (s > 0.f) ? s : 0.2f*s;
    s_al[w][deg-1] = s;
    s_col[w][deg-1] = n;
  }
  float m = -1e30f;
  for (int e = lane; e < deg; e += 64) m = fmaxf(m, s_al[w][e]);
  #pragma unroll
  for (int msk = 1; msk < 64; msk <<= 1) m = fmaxf(m, __shfl_xor(m, msk));
  float z = 0.f;
  for (int e = lane; e < deg; e += 64){ float ex = __expf(s_al[w][e]-m); s_al[w][e] = ex; z += ex; }
  #pragma unroll
  for (int msk = 1; msk < 64; msk <<= 1) z += __shfl_xor(z, msk);
  float inv = 1.0f/(z + 1e-16f);
  for (int e = lane; e < deg; e += 64) s_al[w][e] *= inv;
  int degR = (deg + 3) & ~3;
  for (int e = deg + lane; e < degR; e += 64){ s_al[w][e] = 0.f; s_col[w][e] = n; }
  __syncthreads();
  int half = lane >> 5, cp = lane & 31;
  float a0 = 0.f, a1 = 0.f;
  for (int e = 0; e < degR; e += 4){
    int c0 = s_col[w][e + half], c1 = s_col[w][e + 2 + half];
    u32 q0 = *(const u32*)(xs + (size_t)c0*64 + cp*2);
    u32 q1 = *(const u32*)(xs + (size_t)c1*64 + cp*2);
    float al0 = s_al[w][e + half], al1 = s_al[w][e + 2 + half];
    a0 += al0*bfLO(q0) + al1*bfLO(q1);
    a1 += al0*bfHI(q0) + al1*bfHI(q1);
  }
  a0 += __shfl_xor(a0, 32);
  a1 += __shfl_xor(a1, 32);
  if (half == 0){
    float2 o;
    o.x = fmaxf(a0 + bias[cp*2+0], 0.f);
    o.y = fmaxf(a1 + bias[cp*2+1], 0.f);
    *(float2*)(out + (size_t)n*64 + cp*2) = o;
  }
}

// ---------------- pooling (batch sorted) ----------------
__global__ __launch_bounds__(64) void k_pool(const float* __restrict__ h, const int* __restrict__ batch,
                                             float* __restrict__ pooled, int* __restrict__ cntg){
  int l = threadIdx.x;
  int start = blockIdx.x * 128;
  if (start >= NNODES) return;
  int endn = min(start + 128, NNODES);
  float acc = 0.f;
  int curg = batch[start];
  int run = 0;
  for (int n = start; n < endn; ++n){
    int g = batch[n];
    if (g != curg){
      atomicAdd(&pooled[curg*64+l], acc);
      if (l == 0) atomicAdd(&cntg[curg], run);
      acc = 0.f; run = 0; curg = g;
    }
    acc += h[(size_t)n*64 + l];
    ++run;
  }
  atomicAdd(&pooled[curg*64+l], acc);
  if (l == 0) atomicAdd(&cntg[curg], run);
}

// ---------------- final FFN + softmax ----------------
__global__ void k_ffn(const float* __restrict__ pooled, const int* __restrict__ cntg,
                      const float* __restrict__ og,
                      const float* __restrict__ Wf1, const float* __restrict__ bf1,
                      const float* __restrict__ Wf2, const float* __restrict__ bf2,
                      float* __restrict__ out){
  __shared__ float z[135];
  __shared__ float z1[67];
  __shared__ float o2[2];
  int g = blockIdx.x, t = threadIdx.x;
  if (t < 64) z[t] = pooled[g*64+t] * (1.0f/fmaxf((float)cntg[g], 1.0f));
  else if (t < 135) z[t] = og[g*OGW + (t-64)];
  __syncthreads();
  if (t == 0){
    float s = 0.f;
    for (int k = 0; k < 71; ++k) s += z[64+k]*z[64+k];
    float scale = 1.0f / fmaxf(sqrtf(s), 1e-12f);
    for (int k = 0; k < 71; ++k) z[64+k] *= scale;
  }
  __syncthreads();
  if (t < 67){
    float s = bf1[t];
    for (int d = 0; d < 135; ++d) s += z[d]*Wf1[d*67+t];
    z1[t] = fmaxf(s, 0.f);
  }
  __syncthreads();
  if (t < 2){
    float s = bf2[t];
    for (int j = 0; j < 67; ++j) s += z1[j]*Wf2[j*2+t];
    o2[t] = s;
  }
  __syncthreads();
  if (t == 0){
    float m = fmaxf(o2[0], o2[1]);
    float e0 = expf(o2[0]-m), e1 = expf(o2[1]-m);
    float inv = 1.0f/(e0+e1);
    out[g*2+0] = e0*inv;
    out[g*2+1] = e1*inv;
  }
}

extern "C" void kernel_launch(void* const* d_in, const int* in_sizes, int n_in,
                              void* d_out, int out_size, void* d_ws, size_t ws_size,
                              hipStream_t stream){
  const float* x     = (const float*)d_in[0];
  const int*   ei    = (const int*)d_in[1];
  const float* eattr = (const float*)d_in[2];
  const int*   batch = (const int*)d_in[3];
  const float* W1  = (const float*)d_in[4];
  const float* We1 = (const float*)d_in[5];
  const float* as1 = (const float*)d_in[6];
  const float* ad1 = (const float*)d_in[7];
  const float* ae1 = (const float*)d_in[8];
  const float* b1  = (const float*)d_in[9];
  const float* W2  = (const float*)d_in[10];
  const float* We2 = (const float*)d_in[11];
  const float* as2 = (const float*)d_in[12];
  const float* ad2 = (const float*)d_in[13];
  const float* ae2 = (const float*)d_in[14];
  const float* b2  = (const float*)d_in[15];
  const float* W3  = (const float*)d_in[16];
  const float* We3 = (const float*)d_in[17];
  const float* as3 = (const float*)d_in[18];
  const float* ad3 = (const float*)d_in[19];
  const float* ae3 = (const float*)d_in[20];
  const float* b3  = (const float*)d_in[21];
  const float* Wf1 = (const float*)d_in[22];
  const float* bf1 = (const float*)d_in[23];
  const float* Wf2 = (const float*)d_in[24];
  const float* bf2 = (const float*)d_in[25];
  (void)in_sizes; (void)n_in; (void)out_size; (void)ws_size;
  const int* src = ei;
  const int* dst = ei + NEDGES;
  float* out = (float*)d_out;

  char* base = (char*)d_ws;
  size_t woff = 0;
  auto alloc = [&](size_t bytes)->char*{
    char* p = base + woff;
    woff += (bytes + 255) & ~(size_t)255;
    return p;
  };
  u16*   xsb    = (u16*)  alloc((size_t)NNODES*512*2);
  u16*   hb     = (u16*)  alloc((size_t)NNODES*512*2);
  u16*   xs3b   = (u16*)  alloc((size_t)NNODES*64*2);
  float* h3     = (float*)alloc((size_t)NNODES*64*4);
  u16*   xb     = (u16*)  alloc((size_t)NNODES*64*2);
  u16*   Wt1    = (u16*)  alloc((size_t)512*64*2);
  u16*   Wt2    = (u16*)  alloc((size_t)512*512*2);
  u16*   Wt3    = (u16*)  alloc((size_t)64*512*2);
  float* se1    = (float*)alloc((size_t)NEA*4*4);
  float* se2    = (float*)alloc((size_t)NEA*4*4);
  float* se3    = (float*)alloc((size_t)NEA*4);
  float* ssrc   = (float*)alloc((size_t)NNODES*4*4);
  float* sdst   = (float*)alloc((size_t)NNODES*4*4);
  float* veall  = (float*)alloc(72*9*4);
  int*   gb     = (int*)alloc((size_t)NEDGES*4);
  int*   csroff = (int*)alloc((size_t)(NNODES+1)*4);
  int*   csrsrc = (int*)alloc((size_t)NEA*4);
  int2*  sortedpair = (int2*)alloc((size_t)NEDGES*8);
  int*   goff   = (int*)alloc(NG*4);
  int*   gcur   = (int*)alloc(NG*4);
  int*   csum   = (int*)alloc(NCH*4);
  int*   cbase  = (int*)alloc(NCH*4);
  // ---- zero-initialized region (single memset) ----
  size_t z0 = woff;
  int*   deg    = (int*)alloc((size_t)NNODES*4);
  int*   cnt    = (int*)alloc((size_t)NNODES*4);
  int*   gcnt   = (int*)alloc(NG*4);
  float* og     = (float*)alloc((size_t)NG*OGW*4);
  float* pooled = (float*)alloc((size_t)NG*64*4);
  int*   cntg   = (int*)alloc((size_t)NG*4);
  size_t zlen = woff - z0;

  hipMemsetAsync(base + z0, 0, zlen, stream);

  // prep (casts + ve) fused with deg/gb/gcnt
  k_prep_deg<<<PREPB + EDGEB,256,0,stream>>>(
      x, xb, W1, Wt1, W2, Wt2, W3, Wt3, We1, ae1, We2, ae2, We3, ae3, veall,
      src, dst, batch, deg, gb, gcnt);

  // parallel scans
  k_chunksum<<<NCH,1024,0,stream>>>(deg, csum);
  k_scanmid <<<1,128,0,stream>>>(csum, cbase, gcnt, goff, gcur);
  k_scanout <<<NCH,1024,0,stream>>>(deg, cbase, csroff);

  k_scatter<<<ceil_div(NEDGES+NNODES,256),256,0,stream>>>(src, dst, gb, csroff, cnt, gcur,
                                                          csrsrc, sortedpair);

  // single sorted-gather edge pass: og + se (ILP-2, int2 pair loads)
  k_edge3<<<OGB,256,0,stream>>>(eattr, goff, gcnt, sortedpair, veall, se1, se2, se3, og);

  dim3 g128(4, ceil_div(NNODES,128));

  // ---- layer 1 ----
  k_gemm128<<<g128,256,0,stream>>>(xb, Wt1, xsb, NNODES, 64, as1, ad1, ssrc, sdst);
  k_agg12<<<NNODES/4,256,0,stream>>>(xsb, csroff, csrsrc, ssrc, sdst, se1, b1, hb);

  // ---- layer 2 ----
  k_gemm128<<<g128,256,0,stream>>>(hb, Wt2, xsb, NNODES, 512, as2, ad2, ssrc, sdst);
  k_agg12<<<NNODES/4,256,0,stream>>>(xsb, csroff, csrsrc, ssrc, sdst, se2, b2, hb);

  // ---- layer 3 ----
  k_gemm64<<<ceil_div(NNODES,64),256,0,stream>>>(hb, Wt3, xs3b, NNODES, as3, ad3, ssrc, sdst);
  k_agg3<<<NNODES/4,256,0,stream>>>(xs3b, csroff, csrsrc, ssrc, sdst, se3, b3, h3);

  // ---- pool + FFN ----
  k_pool<<<ceil_div(NNODES,128),64,0,stream>>>(h3, batch, pooled, cntg);
  k_ffn <<<NG,192,0,stream>>>(pooled, cntg, og, Wf1, bf1, Wf2, bf2, out);
}